// Round 13
// baseline (256.001 us; speedup 1.0000x reference)
//
#include <hip/hip_runtime.h>
#include <cstdint>
#include <cstddef>

#define DI __device__ __forceinline__

using f32x4  = __attribute__((ext_vector_type(4))) float;
using bf16x8 = __attribute__((ext_vector_type(8))) short;
using u32x2  = __attribute__((ext_vector_type(2))) unsigned int;
using u32x4  = __attribute__((ext_vector_type(4))) unsigned int;

constexpr int NT = 16384;   // tokens
constexpr int NF = 4096;    // features

// fp32 -> bf16 round-to-nearest-even
DI unsigned short f2bf(float f) {
  union { float f; unsigned u; } v; v.f = f;
  unsigned u = v.u;
  u += 0x7fffu + ((u >> 16) & 1u);
  return (unsigned short)(u >> 16);
}

// async global->LDS, 16B per lane. lds dst is wave-uniform base; HW adds lane*16.
DI void gload_lds16(const void* g, void* l) {
  __builtin_amdgcn_global_load_lds(
      (const __attribute__((address_space(1))) unsigned int*)g,
      (__attribute__((address_space(3))) unsigned int*)l, 16, 0, 0);
}

// raw barrier with counted vmcnt (N newest VMEM ops may stay outstanding)
#define BAR_VM(N)                                              \
  do {                                                         \
    asm volatile("s_waitcnt vmcnt(" #N ")" ::: "memory");      \
    __builtin_amdgcn_s_barrier();                              \
    __builtin_amdgcn_sched_barrier(0);                         \
  } while (0)

// ---------------- prep: factor transpose + bf16 cast (verified r2) ----------------
// f0 [b][c][d] f32 -> f0s [d][b][c] bf16 ; f1 [a][b][c] f32 -> f1s bf16 (same layout)
__global__ void ks_prep(const float* __restrict__ f0, const float* __restrict__ f1,
                        unsigned short* __restrict__ f0s, unsigned short* __restrict__ f1s) {
  int tid = blockIdx.x * 256 + threadIdx.x;     // grid covers 2*262144
  if (tid < 262144) {
    int d = tid & 63, c = (tid >> 6) & 63, b = tid >> 12;
    f0s[d * 4096 + b * 64 + c] = f2bf(f0[tid]);
  } else {
    int t2 = tid - 262144;
    f1s[t2] = f2bf(f1[t2]);
  }
}

// ---------------- stage 1 (r6 dataflow verbatim; Ybuf stride 1040 -> 1028) ---------
// block: 128 tokens x 8 d-planes (wave wv owns d = dg*8+wv, f0 slice persistent).
// y' layout: element = t*4096 + dg*512 + b*8 + dloc   (d-minor 16B chunks for stage2)
// stride 1028 B = 257 dwords (% 32 == 1): Ybuf b16 scatter writes are exact 2-way.
__global__ __launch_bounds__(512, 4) void ks1(
    const float* __restrict__ x, const unsigned short* __restrict__ f0s,
    unsigned short* __restrict__ yp)
{
  __shared__ __align__(16) char L[32768 + 2 * 16448];
  char* const Xb0 = L;
  char* const Xb1 = L + 16384;
  char* const Yb0 = L + 32768;
  char* const Yb1 = L + 32768 + 16448;

  const int w  = blockIdx.x;
  const int tt = (w & 7) | ((w >> 6) << 3);   // siblings (dg 0..7) share XCD
  const int dg = (w >> 3) & 7;
  const long T0 = (long)tt * 128;

  const int tid = threadIdx.x, lane = tid & 63, wv = tid >> 6;
  const int l15 = lane & 15, lq = lane >> 4;
  const int d = dg * 8 + wv;

  bf16x8 fA[4][2];
  #pragma unroll
  for (int bt = 0; bt < 4; ++bt)
    #pragma unroll
    for (int kh = 0; kh < 2; ++kh)
      fA[bt][kh] = *(const bf16x8*)(f0s + (size_t)d * 4096 + (bt * 16 + l15) * 64 + kh * 32 + lq * 8);

  const int st_t = tid >> 5, st_c0 = (tid >> 1) & 15, st_dq = tid & 1;
  const float* const xrow0 = x + (T0 + st_t) * (long)NF + dg * 8 + st_dq * 4;
  const int wkey = (st_t & 7) << 4;

  f32x4 r0, r1, r2, r3;
  auto issue = [&](int st) {
    const float* p = xrow0 + (long)st * 16 * NF + st_c0 * 4 * 64;
    r0 = *(const f32x4*)(p);
    r1 = *(const f32x4*)(p + 64);
    r2 = *(const f32x4*)(p + 128);
    r3 = *(const f32x4*)(p + 192);
  };
  auto stageX = [&](char* X) {
    #pragma unroll
    for (int e = 0; e < 4; ++e) {
      int p = st_dq * 4 + e;
      unsigned lo = (unsigned)f2bf(r0[e]) | ((unsigned)f2bf(r1[e]) << 16);
      unsigned hi = (unsigned)f2bf(r2[e]) | ((unsigned)f2bf(r3[e]) << 16);
      *(u32x2*)(X + p * 2048 + st_t * 128 + ((st_c0 * 8) ^ wkey)) = u32x2{lo, hi};
    }
  };

  issue(0);
  stageX(Xb0);
  issue(1);
  __syncthreads();

  const int rkey = (l15 & 7) << 4;

  for (int st = 0; st < 8; ++st) {
    char* const Xc = (st & 1) ? Xb1 : Xb0;
    char* const Xn = (st & 1) ? Xb0 : Xb1;
    char* const Yc = (st & 1) ? Yb1 : Yb0;

    const char* Xs = Xc + wv * 2048 + l15 * 128;
    bf16x8 bx0 = *(const bf16x8*)(Xs + ((0  + lq * 16) ^ rkey));
    bf16x8 bx1 = *(const bf16x8*)(Xs + ((64 + lq * 16) ^ rkey));
    f32x4 acc[4];
    #pragma unroll
    for (int bt = 0; bt < 4; ++bt) {
      acc[bt] = __builtin_amdgcn_mfma_f32_16x16x32_bf16(fA[bt][0], bx0, (f32x4){0.f,0.f,0.f,0.f}, 0, 0, 0);
      acc[bt] = __builtin_amdgcn_mfma_f32_16x16x32_bf16(fA[bt][1], bx1, acc[bt], 0, 0, 0);
    }

    {
      char* Yw = Yc + l15 * 1028 + wv * 2;
      #pragma unroll
      for (int bt = 0; bt < 4; ++bt)
        #pragma unroll
        for (int i = 0; i < 4; ++i)
          *(unsigned short*)(Yw + (bt * 16 + lq * 4 + i) * 16) = f2bf(acc[bt][i]);
    }

    stageX(Xn);
    issue(st + 2 <= 7 ? st + 2 : 7);
    __syncthreads();

    {
      const char* Yr = Yc;
      #pragma unroll
      for (int h = 0; h < 2; ++h) {
        int t = (tid >> 6) + h * 8;
        int c16 = tid & 63;
        u32x4 v = *(const u32x4*)(Yr + t * 1028 + c16 * 16);
        *(u32x4*)(yp + (T0 + st * 16 + t) * (size_t)NF + dg * 512 + c16 * 8) = v;
      }
    }
  }
}

// ---------------- stage 2 v8: 3-buffer (48KB -> 3 blocks/CU), derived vmcnt --------
// block: 512 thr = 8 waves; wave wv owns a = ag*8+wv; 128 tokens as 8 tiles of 16.
__global__ __launch_bounds__(512, 6) void ks2(
    const unsigned short* __restrict__ yp, const unsigned short* __restrict__ f1s,
    const float* __restrict__ bias, float* __restrict__ out)
{
  __shared__ __align__(16) char Yb[3][16384];   // 3 bufs x [16 t][8 dg][128 B]

  const int bid = blockIdx.x;
  const int ag  = bid & 7;
  const long T0 = (long)(bid >> 3) * 128;

  const int tid = threadIdx.x, lane = tid & 63, wv = tid >> 6;
  const int l15 = lane & 15, lq = lane >> 4;
  const int a = ag * 8 + wv;

  // persistent A operand: f1[a][b2][c2] (32 VGPR) + bias (16 VGPR)
  bf16x8 fa[4][2];
  #pragma unroll
  for (int bt = 0; bt < 4; ++bt)
    #pragma unroll
    for (int kh = 0; kh < 2; ++kh)
      fa[bt][kh] = *(const bf16x8*)(f1s + (size_t)a * 4096 + (bt * 16 + l15) * 64 + kh * 32 + lq * 8);
  f32x4 bv[4];
  #pragma unroll
  for (int bt = 0; bt < 4; ++bt)
    bv[bt] = *(const f32x4*)(bias + a * 64 + bt * 16 + lq * 4);

  // stage one 16-token tile -> buf tile%3: wave wv loads rows {wv, 8+wv};
  // slot s holds global chunk g = s ^ (trow&7) (involution, stays in 128B dg-run)
  auto stage = [&](int tile) {
    char* const dst = Yb[tile % 3];
    #pragma unroll
    for (int i = 0; i < 2; ++i) {
      const int trow = i * 8 + wv;
      const int g = lane ^ (trow & 7);
      const char* src = (const char*)yp + (T0 + (long)tile * 16 + trow) * 8192
                        + ((g >> 3) << 10) + ag * 128 + (g & 7) * 16;
      gload_lds16(src, dst + trow * 1024);
    }
  };

  stage(0); stage(1);
  BAR_VM(2);                 // 4 outstanding; all-but-2 -> stage(0) resident

  #pragma unroll
  for (int j = 0; j < 8; ++j) {
    if (j + 2 < 8) stage(j + 2);      // 2 loads, consumed 2 iters later

    const char* Yr = Yb[j % 3] + l15 * 1024;
    const int sw = wv ^ (l15 & 7);
    bf16x8 c0 = *(const bf16x8*)(Yr + ((lq * 8 + sw) * 16));          // dg = lq
    bf16x8 c1 = *(const bf16x8*)(Yr + (((4 + lq) * 8 + sw) * 16));    // dg = 4+lq
    f32x4 acc[4];
    #pragma unroll
    for (int bt = 0; bt < 4; ++bt) {
      acc[bt] = __builtin_amdgcn_mfma_f32_16x16x32_bf16(fa[bt][0], c0, (f32x4){0.f,0.f,0.f,0.f}, 0, 0, 0);
      acc[bt] = __builtin_amdgcn_mfma_f32_16x16x32_bf16(fa[bt][1], c1, acc[bt], 0, 0, 0);
    }
    float* op = out + (T0 + (long)j * 16 + l15) * NF + a * 64 + lq * 4;
    #pragma unroll
    for (int bt = 0; bt < 4; ++bt)
      *(f32x4*)(op + bt * 16) = acc[bt] + bv[bt];

    // need stage(j+1) resident at barrier; ops newer than it:
    // st(j-1) stores (4, steady) + stage(j+2) loads (2) + st(j) stores (4)
    switch (j) {
      case 0: BAR_VM(6);  break;
      case 1: case 2: case 3: case 4: case 5: BAR_VM(10); break;
      case 6: BAR_VM(8);  break;
      default: break;            // j==7: last tile
    }
  }
}

// ---------------- naive fp32 fallback (only if workspace too small) ----------------
__global__ void ks_naive(const float* __restrict__ x, const float* __restrict__ f0,
                         const float* __restrict__ f1, const float* __restrict__ bias,
                         float* __restrict__ out)
{
  __shared__ float xr[4096];
  __shared__ float yr[4096];
  long t = blockIdx.x;
  int tid = threadIdx.x;
  for (int i = tid; i < 4096; i += 256) xr[i] = x[t * 4096 + i];
  __syncthreads();
  for (int i = tid; i < 4096; i += 256) {
    int b = i >> 6, d = i & 63;
    float s = 0.f;
    for (int c = 0; c < 64; ++c) s += xr[c * 64 + d] * f0[(b * 64 + c) * 64 + d];
    yr[i] = s;
  }
  __syncthreads();
  for (int i = tid; i < 4096; i += 256) {
    int a = i >> 6;
    float s = bias[i];
    for (int c = 0; c < 64; ++c) s += yr[a * 64 + c] * f1[(size_t)i * 64 + c];
    out[t * 4096 + i] = s;
  }
}

extern "C" void kernel_launch(void* const* d_in, const int* in_sizes, int n_in,
                              void* d_out, int out_size, void* d_ws, size_t ws_size,
                              hipStream_t stream) {
  const float* x    = (const float*)d_in[0];
  const float* f0   = (const float*)d_in[1];
  const float* f1   = (const float*)d_in[2];
  const float* bias = (const float*)d_in[3];
  float* out = (float*)d_out;

  const size_t ybytes = (size_t)NT * NF * 2;          // 128 MB bf16 intermediate (y')
  const size_t fbytes = (size_t)64 * 64 * 64 * 2;     // 512 KB per factor
  if (ws_size >= ybytes + 2 * fbytes) {
    unsigned short* yw  = (unsigned short*)d_ws;
    unsigned short* f0s = yw + (size_t)NT * NF;
    unsigned short* f1s = f0s + 64 * 64 * 64;
    ks_prep<<<2048, 256, 0, stream>>>(f0, f1, f0s, f1s);
    ks1<<<1024, 512, 0, stream>>>(x, f0s, yw);
    ks2<<<1024, 512, 0, stream>>>(yw, f1s, bias, out);
  } else {
    ks_naive<<<NT, 256, 0, stream>>>(x, f0, f1, bias, out);
  }
}

// Round 14
// 206.338 us; speedup vs baseline: 1.2407x; 1.2407x over previous
//
#include <hip/hip_runtime.h>
#include <cstdint>
#include <cstddef>

#define DI __device__ __forceinline__

using f32x4  = __attribute__((ext_vector_type(4))) float;
using bf16x8 = __attribute__((ext_vector_type(8))) short;
using u32x2  = __attribute__((ext_vector_type(2))) unsigned int;
using u32x4  = __attribute__((ext_vector_type(4))) unsigned int;

constexpr int NT = 16384;   // tokens
constexpr int NF = 4096;    // features

// y'' layout: 16B chunk(plane, t), plane = b*8 + dg (0..511), chunk holds
// d = dg*8 .. dg*8+7 bf16 for (b, t). byte = (plane*16384 + t)*16.
// Dense in t -> ks1 stores and ks2 loads are 4 x 256B runs per instruction.

// fp32 -> bf16 round-to-nearest-even
DI unsigned short f2bf(float f) {
  union { float f; unsigned u; } v; v.f = f;
  unsigned u = v.u;
  u += 0x7fffu + ((u >> 16) & 1u);
  return (unsigned short)(u >> 16);
}

// ---------------- prep: factor transpose + bf16 cast (verified r2) ----------------
// f0 [b][c][d] f32 -> f0s [d][b][c] bf16 ; f1 [a][b][c] f32 -> f1s bf16 (same layout)
__global__ void ks_prep(const float* __restrict__ f0, const float* __restrict__ f1,
                        unsigned short* __restrict__ f0s, unsigned short* __restrict__ f1s) {
  int tid = blockIdx.x * 256 + threadIdx.x;     // grid covers 2*262144
  if (tid < 262144) {
    int d = tid & 63, c = (tid >> 6) & 63, b = tid >> 12;
    f0s[d * 4096 + b * 64 + c] = f2bf(f0[tid]);
  } else {
    int t2 = tid - 262144;
    f1s[t2] = f2bf(f1[t2]);
  }
}

// ---------------- stage 1 v10: r6 structure; Ybuf [t][d][b] (2-way writes) --------
// block: 128 tokens x 8 d-planes (wave wv owns d = dg*8+wv, f0 slice persistent).
// Ybuf: byte = t*1044 + dloc*128 + b*2  (261 dwords/row; u32x2 writes exact 2-way)
__global__ __launch_bounds__(512, 4) void ks1(
    const float* __restrict__ x, const unsigned short* __restrict__ f0s,
    unsigned short* __restrict__ yp)
{
  __shared__ __align__(16) char L[32768 + 2 * 16704];
  char* const Xb0 = L;
  char* const Xb1 = L + 16384;
  char* const Yb0 = L + 32768;
  char* const Yb1 = L + 32768 + 16704;

  const int w  = blockIdx.x;
  const int tt = (w & 7) | ((w >> 6) << 3);   // siblings (dg 0..7) share XCD
  const int dg = (w >> 3) & 7;
  const long T0 = (long)tt * 128;

  const int tid = threadIdx.x, lane = tid & 63, wv = tid >> 6;
  const int l15 = lane & 15, lq = lane >> 4;
  const int d = dg * 8 + wv;

  bf16x8 fA[4][2];
  #pragma unroll
  for (int bt = 0; bt < 4; ++bt)
    #pragma unroll
    for (int kh = 0; kh < 2; ++kh)
      fA[bt][kh] = *(const bf16x8*)(f0s + (size_t)d * 4096 + (bt * 16 + l15) * 64 + kh * 32 + lq * 8);

  const int st_t = tid >> 5, st_c0 = (tid >> 1) & 15, st_dq = tid & 1;
  const float* const xrow0 = x + (T0 + st_t) * (long)NF + dg * 8 + st_dq * 4;
  const int wkey = (st_t & 7) << 4;

  f32x4 r0, r1, r2, r3;
  auto issue = [&](int st) {
    const float* p = xrow0 + (long)st * 16 * NF + st_c0 * 4 * 64;
    r0 = *(const f32x4*)(p);
    r1 = *(const f32x4*)(p + 64);
    r2 = *(const f32x4*)(p + 128);
    r3 = *(const f32x4*)(p + 192);
  };
  auto stageX = [&](char* X) {
    #pragma unroll
    for (int e = 0; e < 4; ++e) {
      int p = st_dq * 4 + e;
      unsigned lo = (unsigned)f2bf(r0[e]) | ((unsigned)f2bf(r1[e]) << 16);
      unsigned hi = (unsigned)f2bf(r2[e]) | ((unsigned)f2bf(r3[e]) << 16);
      *(u32x2*)(X + p * 2048 + st_t * 128 + ((st_c0 * 8) ^ wkey)) = u32x2{lo, hi};
    }
  };

  issue(0);
  stageX(Xb0);
  issue(1);
  __syncthreads();

  const int rkey = (l15 & 7) << 4;
  const int ct = tid & 15, cb0 = tid >> 4;       // copy-out map: (t, b-base)

  for (int st = 0; st < 8; ++st) {
    char* const Xc = (st & 1) ? Xb1 : Xb0;
    char* const Xn = (st & 1) ? Xb0 : Xb1;
    char* const Yc = (st & 1) ? Yb1 : Yb0;

    const char* Xs = Xc + wv * 2048 + l15 * 128;
    bf16x8 bx0 = *(const bf16x8*)(Xs + ((0  + lq * 16) ^ rkey));
    bf16x8 bx1 = *(const bf16x8*)(Xs + ((64 + lq * 16) ^ rkey));
    f32x4 acc[4];
    #pragma unroll
    for (int bt = 0; bt < 4; ++bt) {
      acc[bt] = __builtin_amdgcn_mfma_f32_16x16x32_bf16(fA[bt][0], bx0, (f32x4){0.f,0.f,0.f,0.f}, 0, 0, 0);
      acc[bt] = __builtin_amdgcn_mfma_f32_16x16x32_bf16(fA[bt][1], bx1, acc[bt], 0, 0, 0);
    }

    // Ybuf write: lane's 4 consecutive b (i=0..3) packed -> u32x2; banks (5t+2lq): 2-way
    {
      char* Yw = Yc + l15 * 1044 + wv * 128 + lq * 8;
      #pragma unroll
      for (int bt = 0; bt < 4; ++bt) {
        unsigned lo = (unsigned)f2bf(acc[bt][0]) | ((unsigned)f2bf(acc[bt][1]) << 16);
        unsigned hi = (unsigned)f2bf(acc[bt][2]) | ((unsigned)f2bf(acc[bt][3]) << 16);
        *(u32x2*)(Yw + bt * 32) = u32x2{lo, hi};
      }
    }

    stageX(Xn);
    issue(st + 2 <= 7 ? st + 2 : 7);
    __syncthreads();

    // copy-out: assemble y'' chunk (8 d) per (b,t); stores = 4 x 256B runs per instr
    #pragma unroll
    for (int h = 0; h < 2; ++h) {
      const int b = cb0 + h * 32;
      const char* Ys = Yc + ct * 1044 + b * 2;
      unsigned short hv[8];
      #pragma unroll
      for (int j = 0; j < 8; ++j) hv[j] = *(const unsigned short*)(Ys + j * 128);
      u32x4 wq;
      #pragma unroll
      for (int m = 0; m < 4; ++m)
        wq[m] = (unsigned)hv[2 * m] | ((unsigned)hv[2 * m + 1] << 16);
      *(u32x4*)((char*)yp + ((size_t)(b * 8 + dg) * 16384 + (T0 + st * 16 + ct)) * 16) = wq;
    }
  }
}

// ---------------- stage 2 v9: LDS-free, barrier-free, dense plane loads -----------
// block: 512 thr = 8 waves; wave wv owns a = ag*8+wv; 128 tokens as 8 tiles of 16.
// B-frag = one y'' chunk per lane; each load instr = 4 x 256B dense runs.
__global__ __launch_bounds__(512, 4) void ks2(
    const unsigned short* __restrict__ yp, const unsigned short* __restrict__ f1s,
    const float* __restrict__ bias, float* __restrict__ out)
{
  const int bid = blockIdx.x;
  const int ag  = bid & 7;
  const long T0 = (long)(bid >> 3) * 128;

  const int tid = threadIdx.x, lane = tid & 63, wv = tid >> 6;
  const int l15 = lane & 15, lq = lane >> 4;
  const int a = ag * 8 + wv;

  // persistent A operand: f1[a][b2][c2] (32 VGPR) + bias (16 VGPR)
  bf16x8 fa[4][2];
  #pragma unroll
  for (int bt = 0; bt < 4; ++bt)
    #pragma unroll
    for (int kh = 0; kh < 2; ++kh)
      fa[bt][kh] = *(const bf16x8*)(f1s + (size_t)a * 4096 + (bt * 16 + l15) * 64 + kh * 32 + lq * 8);
  f32x4 bv[4];
  #pragma unroll
  for (int bt = 0; bt < 4; ++bt)
    bv[bt] = *(const f32x4*)(bias + a * 64 + bt * 16 + lq * 4);

  // B chunks: kh=0 -> plane a*8+lq; kh=1 -> plane a*8+4+lq; +j*256B per tile
  const char* const yb = (const char*)yp + ((size_t)(a * 8 + lq) * 16384 + T0 + l15) * 16;
  constexpr size_t KH1 = (size_t)4 * 16384 * 16;    // +4 planes = 1 MB
  float* const ob = out + (T0 + l15) * (size_t)NF + a * 64 + lq * 4;

  auto compute = [&](int j, bf16x8 c0, bf16x8 c1) {
    f32x4 acc[4];
    #pragma unroll
    for (int bt = 0; bt < 4; ++bt) {
      acc[bt] = __builtin_amdgcn_mfma_f32_16x16x32_bf16(fa[bt][0], c0, (f32x4){0.f,0.f,0.f,0.f}, 0, 0, 0);
      acc[bt] = __builtin_amdgcn_mfma_f32_16x16x32_bf16(fa[bt][1], c1, acc[bt], 0, 0, 0);
    }
    float* op = ob + (size_t)j * 16 * NF;
    #pragma unroll
    for (int bt = 0; bt < 4; ++bt)
      *(f32x4*)(op + bt * 16) = acc[bt] + bv[bt];
  };

  // depth-2 named-register pipeline over 8 tiles of 16 tokens (v6 shape)
  bf16x8 A0 = *(const bf16x8*)(yb);
  bf16x8 A1 = *(const bf16x8*)(yb + KH1);
  bf16x8 B0 = *(const bf16x8*)(yb + 256);
  bf16x8 B1 = *(const bf16x8*)(yb + KH1 + 256);

  #pragma unroll
  for (int j = 0; j < 8; j += 2) {
    bf16x8 nA0 = A0, nA1 = A1, nB0 = B0, nB1 = B1;
    if (j + 2 < 8) {
      nA0 = *(const bf16x8*)(yb + (j + 2) * 256);
      nA1 = *(const bf16x8*)(yb + KH1 + (j + 2) * 256);
    }
    compute(j, A0, A1);
    if (j + 3 < 8) {
      nB0 = *(const bf16x8*)(yb + (j + 3) * 256);
      nB1 = *(const bf16x8*)(yb + KH1 + (j + 3) * 256);
    }
    compute(j + 1, B0, B1);
    A0 = nA0; A1 = nA1; B0 = nB0; B1 = nB1;
  }
}

// ---------------- naive fp32 fallback (only if workspace too small) ----------------
__global__ void ks_naive(const float* __restrict__ x, const float* __restrict__ f0,
                         const float* __restrict__ f1, const float* __restrict__ bias,
                         float* __restrict__ out)
{
  __shared__ float xr[4096];
  __shared__ float yr[4096];
  long t = blockIdx.x;
  int tid = threadIdx.x;
  for (int i = tid; i < 4096; i += 256) xr[i] = x[t * 4096 + i];
  __syncthreads();
  for (int i = tid; i < 4096; i += 256) {
    int b = i >> 6, d = i & 63;
    float s = 0.f;
    for (int c = 0; c < 64; ++c) s += xr[c * 64 + d] * f0[(b * 64 + c) * 64 + d];
    yr[i] = s;
  }
  __syncthreads();
  for (int i = tid; i < 4096; i += 256) {
    int a = i >> 6;
    float s = bias[i];
    for (int c = 0; c < 64; ++c) s += yr[a * 64 + c] * f1[(size_t)i * 64 + c];
    out[t * 4096 + i] = s;
  }
}

extern "C" void kernel_launch(void* const* d_in, const int* in_sizes, int n_in,
                              void* d_out, int out_size, void* d_ws, size_t ws_size,
                              hipStream_t stream) {
  const float* x    = (const float*)d_in[0];
  const float* f0   = (const float*)d_in[1];
  const float* f1   = (const float*)d_in[2];
  const float* bias = (const float*)d_in[3];
  float* out = (float*)d_out;

  const size_t ybytes = (size_t)NT * NF * 2;          // 128 MB bf16 intermediate (y'')
  const size_t fbytes = (size_t)64 * 64 * 64 * 2;     // 512 KB per factor
  if (ws_size >= ybytes + 2 * fbytes) {
    unsigned short* yw  = (unsigned short*)d_ws;
    unsigned short* f0s = yw + (size_t)NT * NF;
    unsigned short* f1s = f0s + 64 * 64 * 64;
    ks_prep<<<2048, 256, 0, stream>>>(f0, f1, f0s, f1s);
    ks1<<<1024, 512, 0, stream>>>(x, f0s, yw);
    ks2<<<1024, 512, 0, stream>>>(yw, f1s, bias, out);
  } else {
    ks_naive<<<NT, 256, 0, stream>>>(x, f0, f1, bias, out);
  }
}

// Round 15
// 201.915 us; speedup vs baseline: 1.2679x; 1.0219x over previous
//
#include <hip/hip_runtime.h>
#include <cstdint>
#include <cstddef>

#define DI __device__ __forceinline__

using f32x4  = __attribute__((ext_vector_type(4))) float;
using bf16x8 = __attribute__((ext_vector_type(8))) short;
using u32x2  = __attribute__((ext_vector_type(2))) unsigned int;
using u32x4  = __attribute__((ext_vector_type(4))) unsigned int;

constexpr int NT = 16384;   // tokens
constexpr int NF = 4096;    // features
constexpr int SLICE = 8192; // tokens per ks1/ks2 interleave slice (y-slice = 64 MB < L3)

// y'' layout: 16B chunk(plane, t), plane = b*8 + dg (0..511), chunk holds
// d = dg*8 .. dg*8+7 bf16 for (b, t). byte = (plane*16384 + t)*16.

// fp32 -> bf16 round-to-nearest-even
DI unsigned short f2bf(float f) {
  union { float f; unsigned u; } v; v.f = f;
  unsigned u = v.u;
  u += 0x7fffu + ((u >> 16) & 1u);
  return (unsigned short)(u >> 16);
}

// ---------------- prep: factor transpose + bf16 cast (verified r2) ----------------
__global__ void ks_prep(const float* __restrict__ f0, const float* __restrict__ f1,
                        unsigned short* __restrict__ f0s, unsigned short* __restrict__ f1s) {
  int tid = blockIdx.x * 256 + threadIdx.x;     // grid covers 2*262144
  if (tid < 262144) {
    int d = tid & 63, c = (tid >> 6) & 63, b = tid >> 12;
    f0s[d * 4096 + b * 64 + c] = f2bf(f0[tid]);
  } else {
    int t2 = tid - 262144;
    f1s[t2] = f2bf(f1[t2]);
  }
}

// ---------------- stage 1 v10 (r14 verbatim + slice base) ----------------
// block: 128 tokens x 8 d-planes; wave wv owns d = dg*8+wv, f0 slice persistent.
// Ybuf: byte = t*1044 + dloc*128 + b*2 (u32x2 writes exact 2-way)
__global__ __launch_bounds__(512, 4) void ks1(
    const float* __restrict__ x, const unsigned short* __restrict__ f0s,
    unsigned short* __restrict__ yp, int tbase)
{
  __shared__ __align__(16) char L[32768 + 2 * 16704];
  char* const Xb0 = L;
  char* const Xb1 = L + 16384;
  char* const Yb0 = L + 32768;
  char* const Yb1 = L + 32768 + 16704;

  const int w  = blockIdx.x;                  // 0..511 per slice
  const int tt = (w & 7) | ((w >> 6) << 3);   // siblings (dg 0..7) share XCD
  const int dg = (w >> 3) & 7;
  const long T0 = (long)tbase + (long)tt * 128;

  const int tid = threadIdx.x, lane = tid & 63, wv = tid >> 6;
  const int l15 = lane & 15, lq = lane >> 4;
  const int d = dg * 8 + wv;

  bf16x8 fA[4][2];
  #pragma unroll
  for (int bt = 0; bt < 4; ++bt)
    #pragma unroll
    for (int kh = 0; kh < 2; ++kh)
      fA[bt][kh] = *(const bf16x8*)(f0s + (size_t)d * 4096 + (bt * 16 + l15) * 64 + kh * 32 + lq * 8);

  const int st_t = tid >> 5, st_c0 = (tid >> 1) & 15, st_dq = tid & 1;
  const float* const xrow0 = x + (T0 + st_t) * (long)NF + dg * 8 + st_dq * 4;
  const int wkey = (st_t & 7) << 4;

  f32x4 r0, r1, r2, r3;
  auto issue = [&](int st) {
    const float* p = xrow0 + (long)st * 16 * NF + st_c0 * 4 * 64;
    r0 = *(const f32x4*)(p);
    r1 = *(const f32x4*)(p + 64);
    r2 = *(const f32x4*)(p + 128);
    r3 = *(const f32x4*)(p + 192);
  };
  auto stageX = [&](char* X) {
    #pragma unroll
    for (int e = 0; e < 4; ++e) {
      int p = st_dq * 4 + e;
      unsigned lo = (unsigned)f2bf(r0[e]) | ((unsigned)f2bf(r1[e]) << 16);
      unsigned hi = (unsigned)f2bf(r2[e]) | ((unsigned)f2bf(r3[e]) << 16);
      *(u32x2*)(X + p * 2048 + st_t * 128 + ((st_c0 * 8) ^ wkey)) = u32x2{lo, hi};
    }
  };

  issue(0);
  stageX(Xb0);
  issue(1);
  __syncthreads();

  const int rkey = (l15 & 7) << 4;
  const int ct = tid & 15, cb0 = tid >> 4;       // copy-out map: (t, b-base)

  for (int st = 0; st < 8; ++st) {
    char* const Xc = (st & 1) ? Xb1 : Xb0;
    char* const Xn = (st & 1) ? Xb0 : Xb1;
    char* const Yc = (st & 1) ? Yb1 : Yb0;

    const char* Xs = Xc + wv * 2048 + l15 * 128;
    bf16x8 bx0 = *(const bf16x8*)(Xs + ((0  + lq * 16) ^ rkey));
    bf16x8 bx1 = *(const bf16x8*)(Xs + ((64 + lq * 16) ^ rkey));
    f32x4 acc[4];
    #pragma unroll
    for (int bt = 0; bt < 4; ++bt) {
      acc[bt] = __builtin_amdgcn_mfma_f32_16x16x32_bf16(fA[bt][0], bx0, (f32x4){0.f,0.f,0.f,0.f}, 0, 0, 0);
      acc[bt] = __builtin_amdgcn_mfma_f32_16x16x32_bf16(fA[bt][1], bx1, acc[bt], 0, 0, 0);
    }

    // Ybuf write: lane's 4 consecutive b packed -> u32x2; banks 2-way (free)
    {
      char* Yw = Yc + l15 * 1044 + wv * 128 + lq * 8;
      #pragma unroll
      for (int bt = 0; bt < 4; ++bt) {
        unsigned lo = (unsigned)f2bf(acc[bt][0]) | ((unsigned)f2bf(acc[bt][1]) << 16);
        unsigned hi = (unsigned)f2bf(acc[bt][2]) | ((unsigned)f2bf(acc[bt][3]) << 16);
        *(u32x2*)(Yw + bt * 32) = u32x2{lo, hi};
      }
    }

    stageX(Xn);
    issue(st + 2 <= 7 ? st + 2 : 7);
    __syncthreads();

    // copy-out: assemble y'' chunk (8 d) per (b,t); stores = 4 x 256B runs per instr
    #pragma unroll
    for (int h = 0; h < 2; ++h) {
      const int b = cb0 + h * 32;
      const char* Ys = Yc + ct * 1044 + b * 2;
      unsigned short hv[8];
      #pragma unroll
      for (int j = 0; j < 8; ++j) hv[j] = *(const unsigned short*)(Ys + j * 128);
      u32x4 wq;
      #pragma unroll
      for (int m = 0; m < 4; ++m)
        wq[m] = (unsigned)hv[2 * m] | ((unsigned)hv[2 * m + 1] << 16);
      *(u32x4*)((char*)yp + ((size_t)(b * 8 + dg) * 16384 + (T0 + st * 16 + ct)) * 16) = wq;
    }
  }
}

// ---------------- stage 2 v9 (r14 verbatim + slice base + nt z-stores) -------------
// block: 512 thr = 8 waves; wave wv owns a = ag*8+wv; 128 tokens as 8 tiles of 16.
// B-frag = one y'' chunk per lane; each load instr = 4 x 256B dense runs.
// z stores non-temporal: z never re-read -> keep L3 space for y''.
__global__ __launch_bounds__(512, 4) void ks2(
    const unsigned short* __restrict__ yp, const unsigned short* __restrict__ f1s,
    const float* __restrict__ bias, float* __restrict__ out, int tbase)
{
  const int bid = blockIdx.x;                 // 0..511 per slice
  const int ag  = bid & 7;
  const long T0 = (long)tbase + (long)(bid >> 3) * 128;

  const int tid = threadIdx.x, lane = tid & 63, wv = tid >> 6;
  const int l15 = lane & 15, lq = lane >> 4;
  const int a = ag * 8 + wv;

  bf16x8 fa[4][2];
  #pragma unroll
  for (int bt = 0; bt < 4; ++bt)
    #pragma unroll
    for (int kh = 0; kh < 2; ++kh)
      fa[bt][kh] = *(const bf16x8*)(f1s + (size_t)a * 4096 + (bt * 16 + l15) * 64 + kh * 32 + lq * 8);
  f32x4 bv[4];
  #pragma unroll
  for (int bt = 0; bt < 4; ++bt)
    bv[bt] = *(const f32x4*)(bias + a * 64 + bt * 16 + lq * 4);

  const char* const yb = (const char*)yp + ((size_t)(a * 8 + lq) * 16384 + T0 + l15) * 16;
  constexpr size_t KH1 = (size_t)4 * 16384 * 16;    // +4 planes
  float* const ob = out + (T0 + l15) * (size_t)NF + a * 64 + lq * 4;

  auto compute = [&](int j, bf16x8 c0, bf16x8 c1) {
    f32x4 acc[4];
    #pragma unroll
    for (int bt = 0; bt < 4; ++bt) {
      acc[bt] = __builtin_amdgcn_mfma_f32_16x16x32_bf16(fa[bt][0], c0, (f32x4){0.f,0.f,0.f,0.f}, 0, 0, 0);
      acc[bt] = __builtin_amdgcn_mfma_f32_16x16x32_bf16(fa[bt][1], c1, acc[bt], 0, 0, 0);
    }
    float* op = ob + (size_t)j * 16 * NF;
    #pragma unroll
    for (int bt = 0; bt < 4; ++bt) {
      f32x4 r = acc[bt] + bv[bt];
      __builtin_nontemporal_store(r, (f32x4*)(op + bt * 16));
    }
  };

  // depth-2 named-register pipeline over 8 tiles of 16 tokens
  bf16x8 A0 = *(const bf16x8*)(yb);
  bf16x8 A1 = *(const bf16x8*)(yb + KH1);
  bf16x8 B0 = *(const bf16x8*)(yb + 256);
  bf16x8 B1 = *(const bf16x8*)(yb + KH1 + 256);

  #pragma unroll
  for (int j = 0; j < 8; j += 2) {
    bf16x8 nA0 = A0, nA1 = A1, nB0 = B0, nB1 = B1;
    if (j + 2 < 8) {
      nA0 = *(const bf16x8*)(yb + (j + 2) * 256);
      nA1 = *(const bf16x8*)(yb + KH1 + (j + 2) * 256);
    }
    compute(j, A0, A1);
    if (j + 3 < 8) {
      nB0 = *(const bf16x8*)(yb + (j + 3) * 256);
      nB1 = *(const bf16x8*)(yb + KH1 + (j + 3) * 256);
    }
    compute(j + 1, B0, B1);
    A0 = nA0; A1 = nA1; B0 = nB0; B1 = nB1;
  }
}

// ---------------- naive fp32 fallback (only if workspace too small) ----------------
__global__ void ks_naive(const float* __restrict__ x, const float* __restrict__ f0,
                         const float* __restrict__ f1, const float* __restrict__ bias,
                         float* __restrict__ out)
{
  __shared__ float xr[4096];
  __shared__ float yr[4096];
  long t = blockIdx.x;
  int tid = threadIdx.x;
  for (int i = tid; i < 4096; i += 256) xr[i] = x[t * 4096 + i];
  __syncthreads();
  for (int i = tid; i < 4096; i += 256) {
    int b = i >> 6, d = i & 63;
    float s = 0.f;
    for (int c = 0; c < 64; ++c) s += xr[c * 64 + d] * f0[(b * 64 + c) * 64 + d];
    yr[i] = s;
  }
  __syncthreads();
  for (int i = tid; i < 4096; i += 256) {
    int a = i >> 6;
    float s = bias[i];
    for (int c = 0; c < 64; ++c) s += yr[a * 64 + c] * f1[(size_t)i * 64 + c];
    out[t * 4096 + i] = s;
  }
}

extern "C" void kernel_launch(void* const* d_in, const int* in_sizes, int n_in,
                              void* d_out, int out_size, void* d_ws, size_t ws_size,
                              hipStream_t stream) {
  const float* x    = (const float*)d_in[0];
  const float* f0   = (const float*)d_in[1];
  const float* f1   = (const float*)d_in[2];
  const float* bias = (const float*)d_in[3];
  float* out = (float*)d_out;

  const size_t ybytes = (size_t)NT * NF * 2;          // 128 MB bf16 intermediate (y'')
  const size_t fbytes = (size_t)64 * 64 * 64 * 2;     // 512 KB per factor
  if (ws_size >= ybytes + 2 * fbytes) {
    unsigned short* yw  = (unsigned short*)d_ws;
    unsigned short* f0s = yw + (size_t)NT * NF;
    unsigned short* f1s = f0s + 64 * 64 * 64;
    ks_prep<<<2048, 256, 0, stream>>>(f0, f1, f0s, f1s);
    // slice-interleaved: consume each y-slice (64 MB) while L3-resident
    for (int s = 0; s < NT / SLICE; ++s) {
      ks1<<<(SLICE / 128) * 8, 512, 0, stream>>>(x, f0s, yw, s * SLICE);
      ks2<<<(SLICE / 128) * 8, 512, 0, stream>>>(yw, f1s, bias, out, s * SLICE);
    }
  } else {
    ks_naive<<<NT, 256, 0, stream>>>(x, f0, f1, bias, out);
  }
}